// Round 5
// baseline (110.246 us; speedup 1.0000x reference)
//
#include <hip/hip_runtime.h>
#include <math.h>

#define PP 4
#define BB 32
#define NN 2048
#define MM 512
#define DLAT 128
#define BETA_C 1e-3f
#define BIGV 1e9f
#define SENT 1e8f
#define THREADS 256

// Cross-kernel scratch as a device global (proven-working config; avoids any
// dependence on d_ws). Layout: [0..127] qual_sum, [128..255] cov_sum,
// [256..383] nx, [384..511] ny. Every cell is unconditionally rewritten by
// parts_kernel each launch -> graph replays do identical work, no stale state.
__device__ float g_ws[4 * PP * BB];

// Quality pass: SLOTS x-points per lane (k = base + s*THREADS + tid), stream
// all M y-points from SoA LDS (broadcast b128 reads, reused across slots).
template<int SLOTS>
__device__ __forceinline__ float quality_pass(
    const float* __restrict__ syx, const float* __restrict__ syy, const float* __restrict__ syz,
    const float* __restrict__ sxx, const float* __restrict__ sxy, const float* __restrict__ sxz,
    int nx, int base, int tid)
{
    float px[SLOTS], py[SLOTS], pz[SLOTS], mna[SLOTS], mnb[SLOTS];
    bool act[SLOTS];
#pragma unroll
    for (int s = 0; s < SLOTS; ++s) {
        int k = base + s * THREADS + tid;
        act[s] = (k < nx);
        px[s] = act[s] ? sxx[k] : SENT;
        py[s] = act[s] ? sxy[k] : SENT;
        pz[s] = act[s] ? sxz[k] : SENT;
        mna[s] = BIGV; mnb[s] = BIGV;
    }
    for (int m = 0; m < MM; m += 4) {
        float4 yx = *reinterpret_cast<const float4*>(syx + m);
        float4 yy = *reinterpret_cast<const float4*>(syy + m);
        float4 yz = *reinterpret_cast<const float4*>(syz + m);
#pragma unroll
        for (int s = 0; s < SLOTS; ++s) {
            float dx0 = px[s] - yx.x, dy0 = py[s] - yy.x, dz0 = pz[s] - yz.x;
            float dx1 = px[s] - yx.y, dy1 = py[s] - yy.y, dz1 = pz[s] - yz.y;
            float dx2 = px[s] - yx.z, dy2 = py[s] - yy.z, dz2 = pz[s] - yz.z;
            float dx3 = px[s] - yx.w, dy3 = py[s] - yy.w, dz3 = pz[s] - yz.w;
            float d0 = dx0 * dx0 + dy0 * dy0 + dz0 * dz0;
            float d1 = dx1 * dx1 + dy1 * dy1 + dz1 * dz1;
            float d2 = dx2 * dx2 + dy2 * dy2 + dz2 * dz2;
            float d3 = dx3 * dx3 + dy3 * dy3 + dz3 * dz3;
            mna[s] = fminf(mna[s], fminf(d0, d1));   // dual chains: break fmin dep latency
            mnb[s] = fminf(mnb[s], fminf(d2, d3));
        }
    }
    float sum = 0.0f;
#pragma unroll
    for (int s = 0; s < SLOTS; ++s)
        if (act[s]) sum += fminf(mna[s], mnb[s]);    // min over valid y; ny==0 -> BIGV (matches ref BIG)
    return sum;
}

// Coverage pass: 2 y-slots per lane (M=512, THREADS=256), stream compacted x
// (padded to nx4 with SENT so b128 stays aligned; sentinel dists ~3e16 never win).
__device__ __forceinline__ float coverage_pass(
    const float* __restrict__ syx, const float* __restrict__ syy, const float* __restrict__ syz,
    const float* __restrict__ sxx, const float* __restrict__ sxy, const float* __restrict__ sxz,
    int nx4, int tid)
{
    float qx[2], qy[2], qz[2], mna[2], mnb[2];
#pragma unroll
    for (int s = 0; s < 2; ++s) {
        int m = s * THREADS + tid;
        qx[s] = syx[m]; qy[s] = syy[m]; qz[s] = syz[m];
        mna[s] = BIGV; mnb[s] = BIGV;
    }
    for (int k = 0; k < nx4; k += 4) {
        float4 xx = *reinterpret_cast<const float4*>(sxx + k);
        float4 xy = *reinterpret_cast<const float4*>(sxy + k);
        float4 xz = *reinterpret_cast<const float4*>(sxz + k);
#pragma unroll
        for (int s = 0; s < 2; ++s) {
            float dx0 = qx[s] - xx.x, dy0 = qy[s] - xy.x, dz0 = qz[s] - xz.x;
            float dx1 = qx[s] - xx.y, dy1 = qy[s] - xy.y, dz1 = qz[s] - xz.y;
            float dx2 = qx[s] - xx.z, dy2 = qy[s] - xy.z, dz2 = qz[s] - xz.z;
            float dx3 = qx[s] - xx.w, dy3 = qy[s] - xy.w, dz3 = qz[s] - xz.w;
            float d0 = dx0 * dx0 + dy0 * dy0 + dz0 * dz0;
            float d1 = dx1 * dx1 + dy1 * dy1 + dz1 * dz1;
            float d2 = dx2 * dx2 + dy2 * dy2 + dz2 * dz2;
            float d3 = dx3 * dx3 + dy3 * dy3 + dz3 * dz3;
            mna[s] = fminf(mna[s], fminf(d0, d1));
            mnb[s] = fminf(mnb[s], fminf(d2, d3));
        }
    }
    float sum = 0.0f;
#pragma unroll
    for (int s = 0; s < 2; ++s)
        if (qx[s] != SENT)                            // valid y only (sentinel marks invalid)
            sum += fminf(mna[s], mnb[s]);             // nx==0 -> loop skipped -> BIGV, matches ref
    return sum;
}

// One block per (batch b, part i, phase). phase 0: quality, phase 1: coverage.
__global__ __launch_bounds__(THREADS) void parts_kernel(
    const float* __restrict__ ipt,    // (B,N,3)
    const float* __restrict__ opt,    // (P,B,M,3)
    const float* __restrict__ trans,  // (P,B,3)
    const float* __restrict__ rots,   // (P,B,4)
    const int*   __restrict__ idx)    // (B,N)
{
    const int b = blockIdx.x;
    const int i = blockIdx.y;
    const int phase = blockIdx.z;
    const int tid = threadIdx.x;

    __shared__ float Rm[12];
    __shared__ int s_nx, s_ny;
    __shared__ __align__(16) float syx[MM], syy[MM], syz[MM];   // SoA y (12B/pt vs 16B AoS)
    __shared__ __align__(16) float sxx[NN], sxy[NN], sxz[NN];   // SoA compacted x
    __shared__ float red[THREADS / 64];

    if (tid == 0) {
        s_nx = 0;
        s_ny = 0;
        const float* q = rots + (i * BB + b) * 4;
        float qw = q[0], qx = q[1], qy = q[2], qz = q[3];
        float inv = 1.0f / sqrtf(qw * qw + qx * qx + qy * qy + qz * qz);
        qw *= inv; qx *= inv; qy *= inv; qz *= inv;
        Rm[0] = 1.0f - 2.0f * (qy * qy + qz * qz);
        Rm[1] = 2.0f * (qx * qy - qw * qz);
        Rm[2] = 2.0f * (qx * qz + qw * qy);
        Rm[3] = 2.0f * (qx * qy + qw * qz);
        Rm[4] = 1.0f - 2.0f * (qx * qx + qz * qz);
        Rm[5] = 2.0f * (qy * qz - qw * qx);
        Rm[6] = 2.0f * (qx * qz - qw * qy);
        Rm[7] = 2.0f * (qy * qz + qw * qx);
        Rm[8] = 1.0f - 2.0f * (qx * qx + qy * qy);
        const float* t = trans + (i * BB + b) * 3;
        Rm[9] = t[0]; Rm[10] = t[1]; Rm[11] = t[2];
    }
    __syncthreads();

    // stage y -> SoA LDS; invalid rows get SENT coords (sentinel, also the valid flag)
    int cnt = 0;
    for (int m = tid; m < MM; m += THREADS) {
        const float* y = opt + (((size_t)i * BB + b) * MM + m) * 3;
        float yx = y[0], yy = y[1], yz = y[2];
        bool v = (yx != 0.0f) | (yy != 0.0f) | (yz != 0.0f);
        if (v) cnt++;
        else { yx = SENT; yy = SENT; yz = SENT; }
        syx[m] = yx; syy[m] = yy; syz[m] = yz;
    }
    if (cnt) atomicAdd(&s_ny, cnt);

    // transform + compact x points of part i (order-independent: only min/sum consumed)
    const float R0 = Rm[0], R1 = Rm[1], R2 = Rm[2];
    const float R3 = Rm[3], R4 = Rm[4], R5 = Rm[5];
    const float R6 = Rm[6], R7 = Rm[7], R8 = Rm[8];
    const float t0 = Rm[9], t1 = Rm[10], t2 = Rm[11];
    for (int n = tid; n < NN; n += THREADS) {
        const float* p = ipt + ((size_t)b * NN + n) * 3;
        float px = p[0], py = p[1], pz = p[2];
        bool nz = (px != 0.0f) | (py != 0.0f) | (pz != 0.0f);
        if (nz && idx[b * NN + n] == i) {
            px -= t0; py -= t1; pz -= t2;
            int pos = atomicAdd(&s_nx, 1);
            sxx[pos] = R0 * px + R1 * py + R2 * pz;
            sxy[pos] = R3 * px + R4 * py + R5 * pz;
            sxz[pos] = R6 * px + R7 * py + R8 * pz;
        }
    }
    __syncthreads();
    const int nx = s_nx;
    const int ny = s_ny;
    const int nx4 = (nx + 3) & ~3;
    if (tid < nx4 - nx) {                 // pad to x4 for aligned b128 streaming
        sxx[nx + tid] = SENT; sxy[nx + tid] = SENT; sxz[nx + tid] = SENT;
    }
    __syncthreads();

    float sum;
    if (phase == 0) {
        if (nx <= 2 * THREADS) {
            sum = quality_pass<2>(syx, syy, syz, sxx, sxy, sxz, nx, 0, tid);
        } else {
            sum = quality_pass<3>(syx, syy, syz, sxx, sxy, sxz, nx, 0, tid);
            for (int k0 = 3 * THREADS; k0 < nx; k0 += THREADS)   // rare generic tail
                sum += quality_pass<1>(syx, syy, syz, sxx, sxy, sxz, nx, k0, tid);
        }
    } else {
        sum = coverage_pass(syx, syy, syz, sxx, sxy, sxz, nx4, tid);
    }

    // block reduction (wave64 shuffle + LDS)
    for (int off = 32; off > 0; off >>= 1) sum += __shfl_down(sum, off);
    if ((tid & 63) == 0) red[tid >> 6] = sum;
    __syncthreads();
    if (tid == 0) {
        float tot = 0.0f;
        for (int w = 0; w < THREADS / 64; ++w) tot += red[w];
        int pb = i * BB + b;
        if (phase == 0) {
            g_ws[pb] = tot;
            g_ws[2 * PP * BB + pb] = (float)nx;
        } else {
            g_ws[PP * BB + pb] = tot;
            g_ws[3 * PP * BB + pb] = (float)ny;
        }
    }
}

__global__ __launch_bounds__(256) void finalize_kernel(
    const float* __restrict__ probs,   // (P,B,1)
    const float* __restrict__ mu,      // (B,DLAT)
    const float* __restrict__ logvar,  // (B,DLAT)
    float* __restrict__ out)
{
    const int tid = threadIdx.x;
    __shared__ float red[4];
    __shared__ float s_wq[PP * BB], s_wc[PP * BB], s_val[PP * BB];

    // KL: sum over B*DLAT of (1 + lv - mu^2 - exp(lv))
    float kls = 0.0f;
    for (int t = tid; t < BB * DLAT; t += 256) {
        float m_ = mu[t], lv = logvar[t];
        kls += 1.0f + lv - m_ * m_ - expf(lv);
    }
    for (int off = 32; off > 0; off >>= 1) kls += __shfl_down(kls, off);
    if ((tid & 63) == 0) red[tid >> 6] = kls;

    if (tid < PP * BB) {
        float qs = g_ws[tid];
        float cs = g_ws[PP * BB + tid];
        float nxf = g_ws[2 * PP * BB + tid];
        float nyf = g_ws[3 * PP * BB + tid];
        bool valid = (nxf > 0.0f) && (nyf > 0.0f);
        float w = valid ? probs[tid] : 0.0f;
        s_wq[tid] = w * (qs / fmaxf(nxf, 1.0f));
        s_wc[tid] = w * (cs / fmaxf(nyf, 1.0f));
        s_val[tid] = valid ? 1.0f : 0.0f;
    }
    __syncthreads();

    if (tid == 0) {
        float kld = -0.5f * (red[0] + red[1] + red[2] + red[3]) / (float)BB;
        float ch = 0.0f, cov = 0.0f, qu = 0.0f, num = 0.0f;
        for (int i = 0; i < PP; ++i) {
            float sq = 0.0f, sc = 0.0f, n = 0.0f;
            for (int bb = 0; bb < BB; ++bb) {
                sq += s_wq[i * BB + bb];
                sc += s_wc[i * BB + bb];
                n += s_val[i * BB + bb];
            }
            float has = (n > 0.0f) ? 1.0f : 0.0f;
            float invn = has / fmaxf(n, 1.0f);
            qu += sq * invn;
            cov += sc * invn;
            ch += (sq + sc) * invn;
            num += has;
        }
        float invnum = 1.0f / fmaxf(num, 1.0f);
        float cds = ch * invnum;
        out[0] = cds + BETA_C * kld;
        out[1] = cds;
        out[2] = cov * invnum;
        out[3] = qu * invnum;
        out[4] = kld;
    }
}

extern "C" void kernel_launch(void* const* d_in, const int* in_sizes, int n_in,
                              void* d_out, int out_size, void* d_ws, size_t ws_size,
                              hipStream_t stream) {
    const float* ipt    = (const float*)d_in[0];
    const float* opt    = (const float*)d_in[1];
    const float* trans  = (const float*)d_in[2];
    const float* rots   = (const float*)d_in[3];
    const float* probs  = (const float*)d_in[4];
    const int*   idx    = (const int*)d_in[5];
    const float* mu     = (const float*)d_in[6];
    const float* logvar = (const float*)d_in[7];
    float* out = (float*)d_out;
    (void)d_ws; (void)ws_size; (void)in_sizes; (void)n_in; (void)out_size;

    dim3 grid(BB, PP, 2);
    parts_kernel<<<grid, THREADS, 0, stream>>>(ipt, opt, trans, rots, idx);
    finalize_kernel<<<1, 256, 0, stream>>>(probs, mu, logvar, out);
}

// Round 6
// 98.856 us; speedup vs baseline: 1.1152x; 1.1152x over previous
//
#include <hip/hip_runtime.h>
#include <math.h>

#define PP 4
#define BB 32
#define PB (PP * BB)
#define NN 2048
#define MM 512
#define DLAT 128
#define BETA_C 1e-3f
#define BIGV 1e9f
#define SENT 1e8f
#define THREADS 256
#define NCHUNK 2
#define QCH (NN / NCHUNK)   // n-range per quality chunk (1024)
#define CCH (MM / NCHUNK)   // y-points per coverage chunk (256) == THREADS

// Device-global scratch, disjoint slot per chunk-block (no atomics, no init).
// [0..1)*PB qual c0 | [1..2) qual c1 | [2..3) cov c0 | [3..4) cov c1
// [4..5) nx c0      | [5..6) nx c1   | [6..7) ny c0  | [7..8) ny c1
// Every cell written by exactly one block each launch -> replay-safe.
__device__ float g_ws[8 * PB];

// Quality: SLOTS x-points per lane (k = base + s*THREADS + tid), stream all M
// y-points from SoA LDS (uniform-address b128 -> broadcast, reused per slot).
template<int SLOTS>
__device__ __forceinline__ float quality_pass(
    const float* __restrict__ syx, const float* __restrict__ syy, const float* __restrict__ syz,
    const float* __restrict__ sxx, const float* __restrict__ sxy, const float* __restrict__ sxz,
    int nx, int base, int tid)
{
    float px[SLOTS], py[SLOTS], pz[SLOTS], mna[SLOTS], mnb[SLOTS];
    bool act[SLOTS];
#pragma unroll
    for (int s = 0; s < SLOTS; ++s) {
        int k = base + s * THREADS + tid;
        act[s] = (k < nx);
        px[s] = act[s] ? sxx[k] : SENT;
        py[s] = act[s] ? sxy[k] : SENT;
        pz[s] = act[s] ? sxz[k] : SENT;
        mna[s] = BIGV; mnb[s] = BIGV;
    }
    for (int m = 0; m < MM; m += 4) {
        float4 yx = *reinterpret_cast<const float4*>(syx + m);
        float4 yy = *reinterpret_cast<const float4*>(syy + m);
        float4 yz = *reinterpret_cast<const float4*>(syz + m);
#pragma unroll
        for (int s = 0; s < SLOTS; ++s) {
            float dx0 = px[s] - yx.x, dy0 = py[s] - yy.x, dz0 = pz[s] - yz.x;
            float dx1 = px[s] - yx.y, dy1 = py[s] - yy.y, dz1 = pz[s] - yz.y;
            float dx2 = px[s] - yx.z, dy2 = py[s] - yy.z, dz2 = pz[s] - yz.z;
            float dx3 = px[s] - yx.w, dy3 = py[s] - yy.w, dz3 = pz[s] - yz.w;
            float d0 = dx0 * dx0 + dy0 * dy0 + dz0 * dz0;
            float d1 = dx1 * dx1 + dy1 * dy1 + dz1 * dz1;
            float d2 = dx2 * dx2 + dy2 * dy2 + dz2 * dz2;
            float d3 = dx3 * dx3 + dy3 * dy3 + dz3 * dz3;
            mna[s] = fminf(mna[s], fminf(d0, d1));   // dual chains break fmin dep latency
            mnb[s] = fminf(mnb[s], fminf(d2, d3));
        }
    }
    float sum = 0.0f;
#pragma unroll
    for (int s = 0; s < SLOTS; ++s)
        if (act[s]) sum += fminf(mna[s], mnb[s]);    // ny==0 -> BIGV, gated by finalize
    return sum;
}

// One block per (b, i, z). z in [0,NCHUNK): quality x-chunk; z in [NCHUNK,2*NCHUNK):
// coverage y-chunk. 1024 blocks -> 4 blocks/CU -> 4 waves/SIMD (latency hiding).
__global__ __launch_bounds__(THREADS) void parts_kernel(
    const float* __restrict__ ipt,    // (B,N,3)
    const float* __restrict__ opt,    // (P,B,M,3)
    const float* __restrict__ trans,  // (P,B,3)
    const float* __restrict__ rots,   // (P,B,4)
    const int*   __restrict__ idx)    // (B,N)
{
    const int b = blockIdx.x;
    const int i = blockIdx.y;
    const int z = blockIdx.z;
    const int tid = threadIdx.x;

    __shared__ float Rm[12];
    __shared__ int s_nx, s_ny;
    __shared__ __align__(16) float syx[MM], syy[MM], syz[MM];   // SoA y (quality only)
    __shared__ __align__(16) float sxx[NN], sxy[NN], sxz[NN];   // SoA compacted x
    __shared__ float red[THREADS / 64];

    if (tid == 0) {
        s_nx = 0;
        s_ny = 0;
        const float* q = rots + (i * BB + b) * 4;
        float qw = q[0], qx = q[1], qy = q[2], qz = q[3];
        float inv = 1.0f / sqrtf(qw * qw + qx * qx + qy * qy + qz * qz);
        qw *= inv; qx *= inv; qy *= inv; qz *= inv;
        Rm[0] = 1.0f - 2.0f * (qy * qy + qz * qz);
        Rm[1] = 2.0f * (qx * qy - qw * qz);
        Rm[2] = 2.0f * (qx * qz + qw * qy);
        Rm[3] = 2.0f * (qx * qy + qw * qz);
        Rm[4] = 1.0f - 2.0f * (qx * qx + qz * qz);
        Rm[5] = 2.0f * (qy * qz - qw * qx);
        Rm[6] = 2.0f * (qx * qz - qw * qy);
        Rm[7] = 2.0f * (qy * qz + qw * qx);
        Rm[8] = 1.0f - 2.0f * (qx * qx + qy * qy);
        const float* t = trans + (i * BB + b) * 3;
        Rm[9] = t[0]; Rm[10] = t[1]; Rm[11] = t[2];
    }
    __syncthreads();

    const float R0 = Rm[0], R1 = Rm[1], R2 = Rm[2];
    const float R3 = Rm[3], R4 = Rm[4], R5 = Rm[5];
    const float R6 = Rm[6], R7 = Rm[7], R8 = Rm[8];
    const float t0 = Rm[9], t1 = Rm[10], t2 = Rm[11];
    const size_t optbase = ((size_t)i * BB + b) * MM;
    const int pb = i * BB + b;

    if (z < NCHUNK) {
        // ---------------- quality x-chunk z ----------------
        // stage full y -> SoA LDS; invalid rows get SENT coords
        for (int m = tid; m < MM; m += THREADS) {
            const float* y = opt + (optbase + m) * 3;
            float yx = y[0], yy = y[1], yz = y[2];
            bool v = (yx != 0.0f) | (yy != 0.0f) | (yz != 0.0f);
            if (!v) { yx = SENT; yy = SENT; yz = SENT; }
            syx[m] = yx; syy[m] = yy; syz[m] = yz;
        }
        // compact + transform x from this block's n-range only (no dup scan)
        const int n0 = z * QCH;
        for (int n = n0 + tid; n < n0 + QCH; n += THREADS) {
            const float* p = ipt + ((size_t)b * NN + n) * 3;
            float px = p[0], py = p[1], pz = p[2];
            bool nz = (px != 0.0f) | (py != 0.0f) | (pz != 0.0f);
            if (nz && idx[b * NN + n] == i) {
                px -= t0; py -= t1; pz -= t2;
                int pos = atomicAdd(&s_nx, 1);
                sxx[pos] = R0 * px + R1 * py + R2 * pz;
                sxy[pos] = R3 * px + R4 * py + R5 * pz;
                sxz[pos] = R6 * px + R7 * py + R8 * pz;
            }
        }
        __syncthreads();
        const int nxc = s_nx;

        float sum;
        if (nxc <= THREADS) {
            sum = quality_pass<1>(syx, syy, syz, sxx, sxy, sxz, nxc, 0, tid);
        } else if (nxc <= 2 * THREADS) {
            sum = quality_pass<2>(syx, syy, syz, sxx, sxy, sxz, nxc, 0, tid);
        } else {
            sum = quality_pass<2>(syx, syy, syz, sxx, sxy, sxz, nxc, 0, tid);
            for (int k0 = 2 * THREADS; k0 < nxc; k0 += THREADS)   // rare skewed tail
                sum += quality_pass<1>(syx, syy, syz, sxx, sxy, sxz, nxc, k0, tid);
        }

        for (int off = 32; off > 0; off >>= 1) sum += __shfl_down(sum, off);
        if ((tid & 63) == 0) red[tid >> 6] = sum;
        __syncthreads();
        if (tid == 0) {
            float tot = red[0] + red[1] + red[2] + red[3];
            g_ws[(0 + z) * PB + pb] = tot;          // qual partial
            g_ws[(4 + z) * PB + pb] = (float)nxc;   // nx partial
        }
    } else {
        // ---------------- coverage y-chunk c ----------------
        const int c = z - NCHUNK;
        // this lane's single y point, straight to registers (no LDS staging)
        const int m = c * CCH + tid;
        const float* y = opt + (optbase + m) * 3;
        float qx = y[0], qy = y[1], qz = y[2];
        bool v = (qx != 0.0f) | (qy != 0.0f) | (qz != 0.0f);
        if (!v) { qx = SENT; qy = SENT; qz = SENT; }
        unsigned long long bal = __ballot(v);
        if ((tid & 63) == 0) atomicAdd(&s_ny, __popcll(bal));

        // compact + transform the FULL x set of part i
        for (int n = tid; n < NN; n += THREADS) {
            const float* p = ipt + ((size_t)b * NN + n) * 3;
            float px = p[0], py = p[1], pz = p[2];
            bool nz = (px != 0.0f) | (py != 0.0f) | (pz != 0.0f);
            if (nz && idx[b * NN + n] == i) {
                px -= t0; py -= t1; pz -= t2;
                int pos = atomicAdd(&s_nx, 1);
                sxx[pos] = R0 * px + R1 * py + R2 * pz;
                sxy[pos] = R3 * px + R4 * py + R5 * pz;
                sxz[pos] = R6 * px + R7 * py + R8 * pz;
            }
        }
        __syncthreads();
        const int nx = s_nx;
        const int ny = s_ny;
        const int nx4 = (nx + 3) & ~3;
        if (tid < nx4 - nx) {             // pad so b128 streaming stays aligned
            sxx[nx + tid] = SENT; sxy[nx + tid] = SENT; sxz[nx + tid] = SENT;
        }
        __syncthreads();

        float mna = BIGV, mnb = BIGV;
        for (int k = 0; k < nx4; k += 4) {   // uniform-address b128 -> broadcast
            float4 xx = *reinterpret_cast<const float4*>(sxx + k);
            float4 xy = *reinterpret_cast<const float4*>(sxy + k);
            float4 xz = *reinterpret_cast<const float4*>(sxz + k);
            float dx0 = qx - xx.x, dy0 = qy - xy.x, dz0 = qz - xz.x;
            float dx1 = qx - xx.y, dy1 = qy - xy.y, dz1 = qz - xz.y;
            float dx2 = qx - xx.z, dy2 = qy - xy.z, dz2 = qz - xz.z;
            float dx3 = qx - xx.w, dy3 = qy - xy.w, dz3 = qz - xz.w;
            float d0 = dx0 * dx0 + dy0 * dy0 + dz0 * dz0;
            float d1 = dx1 * dx1 + dy1 * dy1 + dz1 * dz1;
            float d2 = dx2 * dx2 + dy2 * dy2 + dz2 * dz2;
            float d3 = dx3 * dx3 + dy3 * dy3 + dz3 * dz3;
            mna = fminf(mna, fminf(d0, d1));
            mnb = fminf(mnb, fminf(d2, d3));
        }
        float sum = v ? fminf(mna, mnb) : 0.0f;   // nx==0 -> BIGV, gated in finalize

        for (int off = 32; off > 0; off >>= 1) sum += __shfl_down(sum, off);
        if ((tid & 63) == 0) red[tid >> 6] = sum;
        __syncthreads();
        if (tid == 0) {
            float tot = red[0] + red[1] + red[2] + red[3];
            g_ws[(2 + c) * PB + pb] = tot;          // cov partial
            g_ws[(6 + c) * PB + pb] = (float)ny;    // ny partial
        }
    }
}

__global__ __launch_bounds__(256) void finalize_kernel(
    const float* __restrict__ probs,   // (P,B,1)
    const float* __restrict__ mu,      // (B,DLAT)
    const float* __restrict__ logvar,  // (B,DLAT)
    float* __restrict__ out)
{
    const int tid = threadIdx.x;
    __shared__ float red[4];
    __shared__ float s_wq[PB], s_wc[PB], s_val[PB];

    // KL: sum over B*DLAT of (1 + lv - mu^2 - exp(lv))
    float kls = 0.0f;
    for (int t = tid; t < BB * DLAT; t += 256) {
        float m_ = mu[t], lv = logvar[t];
        kls += 1.0f + lv - m_ * m_ - expf(lv);
    }
    for (int off = 32; off > 0; off >>= 1) kls += __shfl_down(kls, off);
    if ((tid & 63) == 0) red[tid >> 6] = kls;

    if (tid < PB) {
        float qs  = g_ws[0 * PB + tid] + g_ws[1 * PB + tid];
        float cs  = g_ws[2 * PB + tid] + g_ws[3 * PB + tid];
        float nxf = g_ws[4 * PB + tid] + g_ws[5 * PB + tid];
        float nyf = g_ws[6 * PB + tid] + g_ws[7 * PB + tid];
        bool valid = (nxf > 0.0f) && (nyf > 0.0f);
        float w = valid ? probs[tid] : 0.0f;
        s_wq[tid] = w * (qs / fmaxf(nxf, 1.0f));
        s_wc[tid] = w * (cs / fmaxf(nyf, 1.0f));
        s_val[tid] = valid ? 1.0f : 0.0f;
    }
    __syncthreads();

    if (tid == 0) {
        float kld = -0.5f * (red[0] + red[1] + red[2] + red[3]) / (float)BB;
        float ch = 0.0f, cov = 0.0f, qu = 0.0f, num = 0.0f;
        for (int i = 0; i < PP; ++i) {
            float sq = 0.0f, sc = 0.0f, n = 0.0f;
            for (int bb = 0; bb < BB; ++bb) {
                sq += s_wq[i * BB + bb];
                sc += s_wc[i * BB + bb];
                n += s_val[i * BB + bb];
            }
            float has = (n > 0.0f) ? 1.0f : 0.0f;
            float invn = has / fmaxf(n, 1.0f);
            qu += sq * invn;
            cov += sc * invn;
            ch += (sq + sc) * invn;
            num += has;
        }
        float invnum = 1.0f / fmaxf(num, 1.0f);
        float cds = ch * invnum;
        out[0] = cds + BETA_C * kld;
        out[1] = cds;
        out[2] = cov * invnum;
        out[3] = qu * invnum;
        out[4] = kld;
    }
}

extern "C" void kernel_launch(void* const* d_in, const int* in_sizes, int n_in,
                              void* d_out, int out_size, void* d_ws, size_t ws_size,
                              hipStream_t stream) {
    const float* ipt    = (const float*)d_in[0];
    const float* opt    = (const float*)d_in[1];
    const float* trans  = (const float*)d_in[2];
    const float* rots   = (const float*)d_in[3];
    const float* probs  = (const float*)d_in[4];
    const int*   idx    = (const int*)d_in[5];
    const float* mu     = (const float*)d_in[6];
    const float* logvar = (const float*)d_in[7];
    float* out = (float*)d_out;
    (void)d_ws; (void)ws_size; (void)in_sizes; (void)n_in; (void)out_size;

    dim3 grid(BB, PP, 2 * NCHUNK);
    parts_kernel<<<grid, THREADS, 0, stream>>>(ipt, opt, trans, rots, idx);
    finalize_kernel<<<1, 256, 0, stream>>>(probs, mu, logvar, out);
}

// Round 7
// 98.814 us; speedup vs baseline: 1.1157x; 1.0004x over previous
//
#include <hip/hip_runtime.h>
#include <math.h>

#define PP 4
#define BB 32
#define PB (PP * BB)
#define NN 2048
#define MM 512
#define DLAT 128
#define BETA_C 1e-3f
#define BIGV 1e9f
#define SENT 1e8f
#define THREADS 256
#define NCHUNK 2
#define QCH (NN / NCHUNK)   // n-range per quality chunk (1024)
#define CCH (MM / NCHUNK)   // y-points per coverage chunk (256) == THREADS

// Device-global scratch, disjoint slot per chunk-block (no atomics, no init).
// [0..1)*PB qual c0 | [1..2) qual c1 | [2..3) cov c0 | [3..4) cov c1
// [4..5) nx c0      | [5..6) nx c1   | [6..7) ny c0  | [7..8) ny c1
__device__ float g_ws[8 * PB];

// Wave-level compaction helper: returns this lane's write slot (valid only if sel),
// one shared-atomic per wave instead of per lane.
__device__ __forceinline__ int wave_compact_slot(bool sel, int* s_cnt, int tid) {
    unsigned long long bal = __ballot(sel);
    int lofs = __popcll(bal & ((1ull << (tid & 63)) - 1ull));
    int base = 0;
    if ((tid & 63) == 0 && bal) base = atomicAdd(s_cnt, __popcll(bal));
    base = __shfl(base, 0);   // broadcast wave-lane-0's base
    return base + lofs;
}

// Quality: SLOTS x-points per lane, stream all M y-points from SoA LDS
// (uniform-address b128 -> broadcast; unroll 4 keeps 12 reads in flight).
template<int SLOTS>
__device__ __forceinline__ float quality_pass(
    const float* __restrict__ syx, const float* __restrict__ syy, const float* __restrict__ syz,
    const float* __restrict__ sxx, const float* __restrict__ sxy, const float* __restrict__ sxz,
    int nx, int base, int tid)
{
    float px[SLOTS], py[SLOTS], pz[SLOTS], mna[SLOTS], mnb[SLOTS];
    bool act[SLOTS];
#pragma unroll
    for (int s = 0; s < SLOTS; ++s) {
        int k = base + s * THREADS + tid;
        act[s] = (k < nx);
        px[s] = act[s] ? sxx[k] : SENT;
        py[s] = act[s] ? sxy[k] : SENT;
        pz[s] = act[s] ? sxz[k] : SENT;
        mna[s] = BIGV; mnb[s] = BIGV;
    }
#pragma unroll 4
    for (int m = 0; m < MM; m += 4) {
        float4 yx = *reinterpret_cast<const float4*>(syx + m);
        float4 yy = *reinterpret_cast<const float4*>(syy + m);
        float4 yz = *reinterpret_cast<const float4*>(syz + m);
#pragma unroll
        for (int s = 0; s < SLOTS; ++s) {
            float dx0 = px[s] - yx.x, dy0 = py[s] - yy.x, dz0 = pz[s] - yz.x;
            float dx1 = px[s] - yx.y, dy1 = py[s] - yy.y, dz1 = pz[s] - yz.y;
            float dx2 = px[s] - yx.z, dy2 = py[s] - yy.z, dz2 = pz[s] - yz.z;
            float dx3 = px[s] - yx.w, dy3 = py[s] - yy.w, dz3 = pz[s] - yz.w;
            float d0 = dx0 * dx0 + dy0 * dy0 + dz0 * dz0;
            float d1 = dx1 * dx1 + dy1 * dy1 + dz1 * dz1;
            float d2 = dx2 * dx2 + dy2 * dy2 + dz2 * dz2;
            float d3 = dx3 * dx3 + dy3 * dy3 + dz3 * dz3;
            mna[s] = fminf(mna[s], fminf(d0, d1));   // dual chains break fmin dep latency
            mnb[s] = fminf(mnb[s], fminf(d2, d3));
        }
    }
    float sum = 0.0f;
#pragma unroll
    for (int s = 0; s < SLOTS; ++s)
        if (act[s]) sum += fminf(mna[s], mnb[s]);    // ny==0 -> BIGV, gated by finalize
    return sum;
}

// One block per (b, i, z). z in [0,NCHUNK): quality x-chunk; z in [NCHUNK,2*NCHUNK):
// coverage y-chunk. 512 blocks -> 2 blocks/CU -> 2 waves/SIMD.
__global__ __launch_bounds__(THREADS) void parts_kernel(
    const float* __restrict__ ipt,    // (B,N,3)
    const float* __restrict__ opt,    // (P,B,M,3)
    const float* __restrict__ trans,  // (P,B,3)
    const float* __restrict__ rots,   // (P,B,4)
    const int*   __restrict__ idx)    // (B,N)
{
    const int b = blockIdx.x;
    const int i = blockIdx.y;
    const int z = blockIdx.z;
    const int tid = threadIdx.x;

    __shared__ float Rm[12];
    __shared__ int s_nx, s_ny;
    __shared__ __align__(16) float syx[MM], syy[MM], syz[MM];   // SoA y (quality only)
    __shared__ __align__(16) float sxx[NN], sxy[NN], sxz[NN];   // SoA compacted x
    __shared__ float red[THREADS / 64];

    if (tid == 0) {
        s_nx = 0;
        s_ny = 0;
        const float* q = rots + (i * BB + b) * 4;
        float qw = q[0], qx = q[1], qy = q[2], qz = q[3];
        float inv = 1.0f / sqrtf(qw * qw + qx * qx + qy * qy + qz * qz);
        qw *= inv; qx *= inv; qy *= inv; qz *= inv;
        Rm[0] = 1.0f - 2.0f * (qy * qy + qz * qz);
        Rm[1] = 2.0f * (qx * qy - qw * qz);
        Rm[2] = 2.0f * (qx * qz + qw * qy);
        Rm[3] = 2.0f * (qx * qy + qw * qz);
        Rm[4] = 1.0f - 2.0f * (qx * qx + qz * qz);
        Rm[5] = 2.0f * (qy * qz - qw * qx);
        Rm[6] = 2.0f * (qx * qz - qw * qy);
        Rm[7] = 2.0f * (qy * qz + qw * qx);
        Rm[8] = 1.0f - 2.0f * (qx * qx + qy * qy);
        const float* t = trans + (i * BB + b) * 3;
        Rm[9] = t[0]; Rm[10] = t[1]; Rm[11] = t[2];
    }
    __syncthreads();

    const float R0 = Rm[0], R1 = Rm[1], R2 = Rm[2];
    const float R3 = Rm[3], R4 = Rm[4], R5 = Rm[5];
    const float R6 = Rm[6], R7 = Rm[7], R8 = Rm[8];
    const float t0 = Rm[9], t1 = Rm[10], t2 = Rm[11];
    const size_t optbase = ((size_t)i * BB + b) * MM;
    const int pb = i * BB + b;

    if (z < NCHUNK) {
        // ---------------- quality x-chunk z ----------------
        for (int m = tid; m < MM; m += THREADS) {
            const float* y = opt + (optbase + m) * 3;
            float yx = y[0], yy = y[1], yz = y[2];
            bool v = (yx != 0.0f) | (yy != 0.0f) | (yz != 0.0f);
            if (!v) { yx = SENT; yy = SENT; yz = SENT; }
            syx[m] = yx; syy[m] = yy; syz[m] = yz;
        }
        // compact + transform x from this block's n-range (ballot: 1 atomic/wave/iter)
        const int n0 = z * QCH;
        for (int n = n0 + tid; n < n0 + QCH; n += THREADS) {
            const float* p = ipt + ((size_t)b * NN + n) * 3;
            float px = p[0], py = p[1], pz = p[2];
            bool nz = (px != 0.0f) | (py != 0.0f) | (pz != 0.0f);
            bool sel = nz && (idx[b * NN + n] == i);
            int pos = wave_compact_slot(sel, &s_nx, tid);
            if (sel) {
                px -= t0; py -= t1; pz -= t2;
                sxx[pos] = R0 * px + R1 * py + R2 * pz;
                sxy[pos] = R3 * px + R4 * py + R5 * pz;
                sxz[pos] = R6 * px + R7 * py + R8 * pz;
            }
        }
        __syncthreads();
        const int nxc = s_nx;

        float sum;
        if (nxc <= THREADS) {
            sum = quality_pass<1>(syx, syy, syz, sxx, sxy, sxz, nxc, 0, tid);
        } else if (nxc <= 2 * THREADS) {
            sum = quality_pass<2>(syx, syy, syz, sxx, sxy, sxz, nxc, 0, tid);
        } else {
            sum = quality_pass<2>(syx, syy, syz, sxx, sxy, sxz, nxc, 0, tid);
            for (int k0 = 2 * THREADS; k0 < nxc; k0 += THREADS)   // rare skewed tail
                sum += quality_pass<1>(syx, syy, syz, sxx, sxy, sxz, nxc, k0, tid);
        }

        for (int off = 32; off > 0; off >>= 1) sum += __shfl_down(sum, off);
        if ((tid & 63) == 0) red[tid >> 6] = sum;
        __syncthreads();
        if (tid == 0) {
            float tot = red[0] + red[1] + red[2] + red[3];
            g_ws[(0 + z) * PB + pb] = tot;          // qual partial
            g_ws[(4 + z) * PB + pb] = (float)nxc;   // nx partial
        }
    } else {
        // ---------------- coverage y-chunk c ----------------
        const int c = z - NCHUNK;
        const int m = c * CCH + tid;                // lane's single y, in registers
        const float* y = opt + (optbase + m) * 3;
        float qx = y[0], qy = y[1], qz = y[2];
        bool v = (qx != 0.0f) | (qy != 0.0f) | (qz != 0.0f);
        if (!v) { qx = SENT; qy = SENT; qz = SENT; }
        unsigned long long bal = __ballot(v);
        if ((tid & 63) == 0) atomicAdd(&s_ny, __popcll(bal));

        // compact + transform the FULL x set of part i (ballot compaction)
        for (int n = tid; n < NN; n += THREADS) {
            const float* p = ipt + ((size_t)b * NN + n) * 3;
            float px = p[0], py = p[1], pz = p[2];
            bool nz = (px != 0.0f) | (py != 0.0f) | (pz != 0.0f);
            bool sel = nz && (idx[b * NN + n] == i);
            int pos = wave_compact_slot(sel, &s_nx, tid);
            if (sel) {
                px -= t0; py -= t1; pz -= t2;
                sxx[pos] = R0 * px + R1 * py + R2 * pz;
                sxy[pos] = R3 * px + R4 * py + R5 * pz;
                sxz[pos] = R6 * px + R7 * py + R8 * pz;
            }
        }
        __syncthreads();
        const int nx = s_nx;
        const int ny = s_ny;
        const int nx4 = (nx + 3) & ~3;
        if (tid < nx4 - nx) {             // pad so b128 streaming stays aligned
            sxx[nx + tid] = SENT; sxy[nx + tid] = SENT; sxz[nx + tid] = SENT;
        }
        __syncthreads();

        float mna = BIGV, mnb = BIGV;
#pragma unroll 4
        for (int k = 0; k < nx4; k += 4) {   // uniform-address b128 -> broadcast
            float4 xx = *reinterpret_cast<const float4*>(sxx + k);
            float4 xy = *reinterpret_cast<const float4*>(sxy + k);
            float4 xz = *reinterpret_cast<const float4*>(sxz + k);
            float dx0 = qx - xx.x, dy0 = qy - xy.x, dz0 = qz - xz.x;
            float dx1 = qx - xx.y, dy1 = qy - xy.y, dz1 = qz - xz.y;
            float dx2 = qx - xx.z, dy2 = qy - xy.z, dz2 = qz - xz.z;
            float dx3 = qx - xx.w, dy3 = qy - xy.w, dz3 = qz - xz.w;
            float d0 = dx0 * dx0 + dy0 * dy0 + dz0 * dz0;
            float d1 = dx1 * dx1 + dy1 * dy1 + dz1 * dz1;
            float d2 = dx2 * dx2 + dy2 * dy2 + dz2 * dz2;
            float d3 = dx3 * dx3 + dy3 * dy3 + dz3 * dz3;
            mna = fminf(mna, fminf(d0, d1));
            mnb = fminf(mnb, fminf(d2, d3));
        }
        float sum = v ? fminf(mna, mnb) : 0.0f;   // nx==0 -> BIGV, gated in finalize

        for (int off = 32; off > 0; off >>= 1) sum += __shfl_down(sum, off);
        if ((tid & 63) == 0) red[tid >> 6] = sum;
        __syncthreads();
        if (tid == 0) {
            float tot = red[0] + red[1] + red[2] + red[3];
            g_ws[(2 + c) * PB + pb] = tot;          // cov partial
            g_ws[(6 + c) * PB + pb] = (float)ny;    // ny partial
        }
    }
}

__global__ __launch_bounds__(256) void finalize_kernel(
    const float* __restrict__ probs,   // (P,B,1)
    const float* __restrict__ mu,      // (B,DLAT)
    const float* __restrict__ logvar,  // (B,DLAT)
    float* __restrict__ out)
{
    const int tid = threadIdx.x;
    __shared__ float red[4];
    __shared__ float s_wq[PB], s_wc[PB], s_val[PB];

    float kls = 0.0f;
    for (int t = tid; t < BB * DLAT; t += 256) {
        float m_ = mu[t], lv = logvar[t];
        kls += 1.0f + lv - m_ * m_ - expf(lv);
    }
    for (int off = 32; off > 0; off >>= 1) kls += __shfl_down(kls, off);
    if ((tid & 63) == 0) red[tid >> 6] = kls;

    if (tid < PB) {
        float qs  = g_ws[0 * PB + tid] + g_ws[1 * PB + tid];
        float cs  = g_ws[2 * PB + tid] + g_ws[3 * PB + tid];
        float nxf = g_ws[4 * PB + tid] + g_ws[5 * PB + tid];
        float nyf = g_ws[6 * PB + tid] + g_ws[7 * PB + tid];
        bool valid = (nxf > 0.0f) && (nyf > 0.0f);
        float w = valid ? probs[tid] : 0.0f;
        s_wq[tid] = w * (qs / fmaxf(nxf, 1.0f));
        s_wc[tid] = w * (cs / fmaxf(nyf, 1.0f));
        s_val[tid] = valid ? 1.0f : 0.0f;
    }
    __syncthreads();

    if (tid == 0) {
        float kld = -0.5f * (red[0] + red[1] + red[2] + red[3]) / (float)BB;
        float ch = 0.0f, cov = 0.0f, qu = 0.0f, num = 0.0f;
        for (int i = 0; i < PP; ++i) {
            float sq = 0.0f, sc = 0.0f, n = 0.0f;
            for (int bb = 0; bb < BB; ++bb) {
                sq += s_wq[i * BB + bb];
                sc += s_wc[i * BB + bb];
                n += s_val[i * BB + bb];
            }
            float has = (n > 0.0f) ? 1.0f : 0.0f;
            float invn = has / fmaxf(n, 1.0f);
            qu += sq * invn;
            cov += sc * invn;
            ch += (sq + sc) * invn;
            num += has;
        }
        float invnum = 1.0f / fmaxf(num, 1.0f);
        float cds = ch * invnum;
        out[0] = cds + BETA_C * kld;
        out[1] = cds;
        out[2] = cov * invnum;
        out[3] = qu * invnum;
        out[4] = kld;
    }
}

extern "C" void kernel_launch(void* const* d_in, const int* in_sizes, int n_in,
                              void* d_out, int out_size, void* d_ws, size_t ws_size,
                              hipStream_t stream) {
    const float* ipt    = (const float*)d_in[0];
    const float* opt    = (const float*)d_in[1];
    const float* trans  = (const float*)d_in[2];
    const float* rots   = (const float*)d_in[3];
    const float* probs  = (const float*)d_in[4];
    const int*   idx    = (const int*)d_in[5];
    const float* mu     = (const float*)d_in[6];
    const float* logvar = (const float*)d_in[7];
    float* out = (float*)d_out;
    (void)d_ws; (void)ws_size; (void)in_sizes; (void)n_in; (void)out_size;

    dim3 grid(BB, PP, 2 * NCHUNK);
    parts_kernel<<<grid, THREADS, 0, stream>>>(ipt, opt, trans, rots, idx);
    finalize_kernel<<<1, 256, 0, stream>>>(probs, mu, logvar, out);
}

// Round 8
// 95.234 us; speedup vs baseline: 1.1576x; 1.0376x over previous
//
#include <hip/hip_runtime.h>
#include <math.h>

#define PP 4
#define BB 32
#define PB (PP * BB)
#define NN 2048
#define MM 512
#define DLAT 128
#define BETA_C 1e-3f
#define BIGV 1e9f
#define SENT 1e8f
#define THREADS 512
#define NWAVE (THREADS / 64)      // 8 waves/block
#define NCHUNK 2
#define QCH (NN / NCHUNK)         // 1024 n-range per quality chunk
#define CCH (MM / NCHUNK)         // 256 y per coverage chunk
#define XMAX (NN + 32)            // compacted-x capacity incl. pad

// Device-global scratch, disjoint slot per chunk-block (no atomics, no init).
// [0..1)*PB qual c0 | [1..2) qual c1 | [2..3) cov c0 | [3..4) cov c1
// [4..5) nx c0      | [5..6) nx c1   | [6..7) ny c0  | [7..8) ny c1
__device__ float g_ws[8 * PB];

__device__ __forceinline__ int wave_compact_slot(bool sel, int* s_cnt, int tid) {
    unsigned long long bal = __ballot(sel);
    int lofs = __popcll(bal & ((1ull << (tid & 63)) - 1ull));
    int base = 0;
    if ((tid & 63) == 0 && bal) base = atomicAdd(s_cnt, __popcll(bal));
    base = __shfl(base, 0);
    return base + lofs;
}

// One block per (b, i, z). z<NCHUNK: quality x-chunk; else coverage y-chunk.
// 512 blocks x 512 thr -> 2 blocks/CU -> 4 waves/SIMD. Each lane holds 4
// register points; each wave streams 1/8 of the opposing set from LDS
// (4x fewer ds_read_b128 than one-slot streaming); wave partial minima are
// combined through pmin[][].
__global__ __launch_bounds__(THREADS) void parts_kernel(
    const float* __restrict__ ipt,    // (B,N,3)
    const float* __restrict__ opt,    // (P,B,M,3)
    const float* __restrict__ trans,  // (P,B,3)
    const float* __restrict__ rots,   // (P,B,4)
    const int*   __restrict__ idx)    // (B,N)
{
    const int b = blockIdx.x;
    const int i = blockIdx.y;
    const int z = blockIdx.z;
    const int tid = threadIdx.x;
    const int lane = tid & 63;
    const int w = tid >> 6;

    __shared__ float Rm[12];
    __shared__ int s_nx, s_ny;
    __shared__ __align__(16) float syx[MM], syy[MM], syz[MM];
    __shared__ __align__(16) float sxx[XMAX], sxy[XMAX], sxz[XMAX];
    __shared__ float pmin[NWAVE][256];
    __shared__ float red[NWAVE];

    if (tid == 0) {
        s_nx = 0;
        s_ny = 0;
        const float* q = rots + (i * BB + b) * 4;
        float qw = q[0], qx = q[1], qy = q[2], qz = q[3];
        float inv = 1.0f / sqrtf(qw * qw + qx * qx + qy * qy + qz * qz);
        qw *= inv; qx *= inv; qy *= inv; qz *= inv;
        Rm[0] = 1.0f - 2.0f * (qy * qy + qz * qz);
        Rm[1] = 2.0f * (qx * qy - qw * qz);
        Rm[2] = 2.0f * (qx * qz + qw * qy);
        Rm[3] = 2.0f * (qx * qy + qw * qz);
        Rm[4] = 1.0f - 2.0f * (qx * qx + qz * qz);
        Rm[5] = 2.0f * (qy * qz - qw * qx);
        Rm[6] = 2.0f * (qx * qz - qw * qy);
        Rm[7] = 2.0f * (qy * qz + qw * qx);
        Rm[8] = 1.0f - 2.0f * (qx * qx + qy * qy);
        const float* t = trans + (i * BB + b) * 3;
        Rm[9] = t[0]; Rm[10] = t[1]; Rm[11] = t[2];
    }
    __syncthreads();

    const float R0 = Rm[0], R1 = Rm[1], R2 = Rm[2];
    const float R3 = Rm[3], R4 = Rm[4], R5 = Rm[5];
    const float R6 = Rm[6], R7 = Rm[7], R8 = Rm[8];
    const float t0 = Rm[9], t1 = Rm[10], t2 = Rm[11];
    const size_t optbase = ((size_t)i * BB + b) * MM;
    const int pb = i * BB + b;

    float sum = 0.0f;

    if (z < NCHUNK) {
        // ---------------- quality x-chunk z ----------------
        for (int m = tid; m < MM; m += THREADS) {
            const float* y = opt + (optbase + m) * 3;
            float yx = y[0], yy = y[1], yz = y[2];
            bool v = (yx != 0.0f) | (yy != 0.0f) | (yz != 0.0f);
            if (!v) { yx = SENT; yy = SENT; yz = SENT; }
            syx[m] = yx; syy[m] = yy; syz[m] = yz;
        }
        const int n0 = z * QCH;
        for (int n = n0 + tid; n < n0 + QCH; n += THREADS) {
            const float* p = ipt + ((size_t)b * NN + n) * 3;
            float px = p[0], py = p[1], pz = p[2];
            bool nz = (px != 0.0f) | (py != 0.0f) | (pz != 0.0f);
            bool sel = nz && (idx[b * NN + n] == i);
            int pos = wave_compact_slot(sel, &s_nx, tid);
            if (sel) {
                px -= t0; py -= t1; pz -= t2;
                sxx[pos] = R0 * px + R1 * py + R2 * pz;
                sxy[pos] = R3 * px + R4 * py + R5 * pz;
                sxz[pos] = R6 * px + R7 * py + R8 * pz;
            }
        }
        __syncthreads();
        const int nxc = s_nx;
        const int y0 = w * (MM / NWAVE);   // this wave's 64-y stream

        for (int base = 0; base < nxc; base += 256) {   // usually one pass
            float px[4], py[4], pz[4], mn[4];
#pragma unroll
            for (int s = 0; s < 4; ++s) {
                int k = base + s * 64 + lane;
                bool a = (k < nxc);
                px[s] = a ? sxx[k] : SENT;
                py[s] = a ? sxy[k] : SENT;
                pz[s] = a ? sxz[k] : SENT;
                mn[s] = BIGV;
            }
#pragma unroll 4
            for (int j = 0; j < MM / NWAVE; j += 4) {   // wave-uniform broadcast b128
                float4 yx = *reinterpret_cast<const float4*>(syx + y0 + j);
                float4 yy = *reinterpret_cast<const float4*>(syy + y0 + j);
                float4 yz = *reinterpret_cast<const float4*>(syz + y0 + j);
#pragma unroll
                for (int s = 0; s < 4; ++s) {
                    float dx0 = px[s] - yx.x, dy0 = py[s] - yy.x, dz0 = pz[s] - yz.x;
                    float dx1 = px[s] - yx.y, dy1 = py[s] - yy.y, dz1 = pz[s] - yz.y;
                    float dx2 = px[s] - yx.z, dy2 = py[s] - yy.z, dz2 = pz[s] - yz.z;
                    float dx3 = px[s] - yx.w, dy3 = py[s] - yy.w, dz3 = pz[s] - yz.w;
                    float d0 = dx0 * dx0 + dy0 * dy0 + dz0 * dz0;
                    float d1 = dx1 * dx1 + dy1 * dy1 + dz1 * dz1;
                    float d2 = dx2 * dx2 + dy2 * dy2 + dz2 * dz2;
                    float d3 = dx3 * dx3 + dy3 * dy3 + dz3 * dz3;
                    mn[s] = fminf(mn[s], fminf(fminf(d0, d1), fminf(d2, d3)));
                }
            }
#pragma unroll
            for (int s = 0; s < 4; ++s) pmin[w][s * 64 + lane] = mn[s];
            __syncthreads();
            if (tid < 256) {
                int j = tid;
                if (base + j < nxc) {
                    float m = pmin[0][j];
#pragma unroll
                    for (int ww = 1; ww < NWAVE; ++ww) m = fminf(m, pmin[ww][j]);
                    sum += m;           // min over this x's 8 wave-partials
                }
            }
            __syncthreads();            // protect pmin for a possible next pass
        }

        for (int off = 32; off > 0; off >>= 1) sum += __shfl_down(sum, off);
        if (lane == 0) red[w] = sum;
        __syncthreads();
        if (tid == 0) {
            float tot = 0.0f;
            for (int ww = 0; ww < NWAVE; ++ww) tot += red[ww];
            g_ws[(0 + z) * PB + pb] = tot;          // qual partial
            g_ws[(4 + z) * PB + pb] = (float)s_nx;  // nx partial
        }
    } else {
        // ---------------- coverage y-chunk c ----------------
        const int c = z - NCHUNK;
        if (tid < CCH) {                            // stage this chunk's 256 y
            const float* y = opt + (optbase + c * CCH + tid) * 3;
            float yx = y[0], yy = y[1], yz = y[2];
            bool v = (yx != 0.0f) | (yy != 0.0f) | (yz != 0.0f);
            if (!v) { yx = SENT; yy = SENT; yz = SENT; }
            syx[tid] = yx; syy[tid] = yy; syz[tid] = yz;
            unsigned long long bal = __ballot(v);   // waves 0-3 fully inside
            if (lane == 0) atomicAdd(&s_ny, __popcll(bal));
        }
        for (int n = tid; n < NN; n += THREADS) {   // compact FULL x of part i
            const float* p = ipt + ((size_t)b * NN + n) * 3;
            float px = p[0], py = p[1], pz = p[2];
            bool nz = (px != 0.0f) | (py != 0.0f) | (pz != 0.0f);
            bool sel = nz && (idx[b * NN + n] == i);
            int pos = wave_compact_slot(sel, &s_nx, tid);
            if (sel) {
                px -= t0; py -= t1; pz -= t2;
                sxx[pos] = R0 * px + R1 * py + R2 * pz;
                sxy[pos] = R3 * px + R4 * py + R5 * pz;
                sxz[pos] = R6 * px + R7 * py + R8 * pz;
            }
        }
        __syncthreads();
        const int nx = s_nx;
        const int ny = s_ny;
        const int nx32 = (nx + 31) & ~31;           // 8 wave-quarters, each %4==0
        if (tid < nx32 - nx) {
            sxx[nx + tid] = SENT; sxy[nx + tid] = SENT; sxz[nx + tid] = SENT;
        }
        __syncthreads();

        float qx[4], qy[4], qz[4], mn[4];
#pragma unroll
        for (int s = 0; s < 4; ++s) {               // lane's 4 y slots (stride-1: free)
            int j = s * 64 + lane;
            qx[s] = syx[j]; qy[s] = syy[j]; qz[s] = syz[j];
            mn[s] = BIGV;
        }
        const int q = nx32 / NWAVE;
        const int x0 = w * q;
#pragma unroll 4
        for (int k = 0; k < q; k += 4) {            // wave-uniform broadcast b128
            float4 xx = *reinterpret_cast<const float4*>(sxx + x0 + k);
            float4 xy = *reinterpret_cast<const float4*>(sxy + x0 + k);
            float4 xz = *reinterpret_cast<const float4*>(sxz + x0 + k);
#pragma unroll
            for (int s = 0; s < 4; ++s) {
                float dx0 = qx[s] - xx.x, dy0 = qy[s] - xy.x, dz0 = qz[s] - xz.x;
                float dx1 = qx[s] - xx.y, dy1 = qy[s] - xy.y, dz1 = qz[s] - xz.y;
                float dx2 = qx[s] - xx.z, dy2 = qy[s] - xy.z, dz2 = qz[s] - xz.z;
                float dx3 = qx[s] - xx.w, dy3 = qy[s] - xy.w, dz3 = qz[s] - xz.w;
                float d0 = dx0 * dx0 + dy0 * dy0 + dz0 * dz0;
                float d1 = dx1 * dx1 + dy1 * dy1 + dz1 * dz1;
                float d2 = dx2 * dx2 + dy2 * dy2 + dz2 * dz2;
                float d3 = dx3 * dx3 + dy3 * dy3 + dz3 * dz3;
                mn[s] = fminf(mn[s], fminf(fminf(d0, d1), fminf(d2, d3)));
            }
        }
#pragma unroll
        for (int s = 0; s < 4; ++s) pmin[w][s * 64 + lane] = mn[s];  // BIGV if q==0
        __syncthreads();
        if (tid < CCH) {
            int j = tid;
            if (syx[j] != SENT) {                   // valid y only
                float m = pmin[0][j];
#pragma unroll
                for (int ww = 1; ww < NWAVE; ++ww) m = fminf(m, pmin[ww][j]);
                sum += m;                           // nx==0 -> BIGV, gated in finalize
            }
        }
        __syncthreads();

        for (int off = 32; off > 0; off >>= 1) sum += __shfl_down(sum, off);
        if (lane == 0) red[w] = sum;
        __syncthreads();
        if (tid == 0) {
            float tot = 0.0f;
            for (int ww = 0; ww < NWAVE; ++ww) tot += red[ww];
            g_ws[(2 + c) * PB + pb] = tot;          // cov partial
            g_ws[(6 + c) * PB + pb] = (float)ny;    // ny partial
        }
    }
}

__global__ __launch_bounds__(256) void finalize_kernel(
    const float* __restrict__ probs,   // (P,B,1)
    const float* __restrict__ mu,      // (B,DLAT)
    const float* __restrict__ logvar,  // (B,DLAT)
    float* __restrict__ out)
{
    const int tid = threadIdx.x;
    __shared__ float red[4];
    __shared__ float s_wq[PB], s_wc[PB], s_val[PB];

    // KL over B*DLAT, float4-vectorized
    const float4* mu4 = reinterpret_cast<const float4*>(mu);
    const float4* lv4 = reinterpret_cast<const float4*>(logvar);
    float kls = 0.0f;
    for (int t = tid; t < BB * DLAT / 4; t += 256) {
        float4 m4 = mu4[t], l4 = lv4[t];
        kls += (1.0f + l4.x - m4.x * m4.x - expf(l4.x))
             + (1.0f + l4.y - m4.y * m4.y - expf(l4.y))
             + (1.0f + l4.z - m4.z * m4.z - expf(l4.z))
             + (1.0f + l4.w - m4.w * m4.w - expf(l4.w));
    }
    for (int off = 32; off > 0; off >>= 1) kls += __shfl_down(kls, off);
    if ((tid & 63) == 0) red[tid >> 6] = kls;

    if (tid < PB) {
        float qs  = g_ws[0 * PB + tid] + g_ws[1 * PB + tid];
        float cs  = g_ws[2 * PB + tid] + g_ws[3 * PB + tid];
        float nxf = g_ws[4 * PB + tid] + g_ws[5 * PB + tid];
        float nyf = g_ws[6 * PB + tid] + g_ws[7 * PB + tid];
        bool valid = (nxf > 0.0f) && (nyf > 0.0f);
        float w = valid ? probs[tid] : 0.0f;
        s_wq[tid] = w * (qs / fmaxf(nxf, 1.0f));
        s_wc[tid] = w * (cs / fmaxf(nyf, 1.0f));
        s_val[tid] = valid ? 1.0f : 0.0f;
    }
    __syncthreads();

    if (tid == 0) {
        float kld = -0.5f * (red[0] + red[1] + red[2] + red[3]) / (float)BB;
        float ch = 0.0f, cov = 0.0f, qu = 0.0f, num = 0.0f;
        for (int i = 0; i < PP; ++i) {
            float sq = 0.0f, sc = 0.0f, n = 0.0f;
            for (int bb = 0; bb < BB; ++bb) {
                sq += s_wq[i * BB + bb];
                sc += s_wc[i * BB + bb];
                n += s_val[i * BB + bb];
            }
            float has = (n > 0.0f) ? 1.0f : 0.0f;
            float invn = has / fmaxf(n, 1.0f);
            qu += sq * invn;
            cov += sc * invn;
            ch += (sq + sc) * invn;
            num += has;
        }
        float invnum = 1.0f / fmaxf(num, 1.0f);
        float cds = ch * invnum;
        out[0] = cds + BETA_C * kld;
        out[1] = cds;
        out[2] = cov * invnum;
        out[3] = qu * invnum;
        out[4] = kld;
    }
}

extern "C" void kernel_launch(void* const* d_in, const int* in_sizes, int n_in,
                              void* d_out, int out_size, void* d_ws, size_t ws_size,
                              hipStream_t stream) {
    const float* ipt    = (const float*)d_in[0];
    const float* opt    = (const float*)d_in[1];
    const float* trans  = (const float*)d_in[2];
    const float* rots   = (const float*)d_in[3];
    const float* probs  = (const float*)d_in[4];
    const int*   idx    = (const int*)d_in[5];
    const float* mu     = (const float*)d_in[6];
    const float* logvar = (const float*)d_in[7];
    float* out = (float*)d_out;
    (void)d_ws; (void)ws_size; (void)in_sizes; (void)n_in; (void)out_size;

    dim3 grid(BB, PP, 2 * NCHUNK);
    parts_kernel<<<grid, THREADS, 0, stream>>>(ipt, opt, trans, rots, idx);
    finalize_kernel<<<1, 256, 0, stream>>>(probs, mu, logvar, out);
}